// Round 4
// baseline (7466.227 us; speedup 1.0000x reference)
//
#include <hip/hip_runtime.h>

#define LYR 6
#define NH 12
#define DM 49
#define FFD 1024
#define NOUT 10
#define NB 8192

typedef __bf16 bf16x8 __attribute__((ext_vector_type(8)));
typedef float f32x4 __attribute__((ext_vector_type(4)));
typedef unsigned int u32;
typedef u32 u32x2 __attribute__((ext_vector_type(2)));
typedef u32 u32x4 __attribute__((ext_vector_type(4)));

static __device__ __forceinline__ f32x4 mfma_hz(u32 a0, u32 a1, u32 b0, u32 b1, f32x4 c) {
  u32x4 A = {a0, a1, 0u, 0u};
  u32x4 B = {b0, b1, 0u, 0u};
  return __builtin_amdgcn_mfma_f32_16x16x32_bf16(
      __builtin_bit_cast(bf16x8, A), __builtin_bit_cast(bf16x8, B), c, 0, 0, 0);
}

static __device__ __forceinline__ unsigned short f2bf(float f) {
  union { float f; unsigned u; } c; c.f = f;
  unsigned r = c.u + 0x7fffu + ((c.u >> 16) & 1u);
  return (unsigned short)(r >> 16);
}

static __device__ __forceinline__ u32 pk2(float a, float b) {
  return (u32)f2bf(a) | ((u32)f2bf(b) << 16);
}

// ================= prep: fragment-linear bf16 weights =================
// Layout per matrix: [tile(4)][kc(4)][lane(64)][j(4)] ushorts.
// value(tile,kc,lane,j) = W_aug[k = 16*kc + 4*(lane>>4) + j][col = 16*tile + (lane&15)]

__global__ void prep_qkv_frag(const float* __restrict__ Wq, const float* __restrict__ bq,
                              const float* __restrict__ Wk, const float* __restrict__ bk,
                              const float* __restrict__ Wv, const float* __restrict__ bv,
                              unsigned short* __restrict__ QF, unsigned short* __restrict__ KF,
                              unsigned short* __restrict__ VF) {
  int lh = blockIdx.x;
  for (int idx = threadIdx.x; idx < 1024; idx += blockDim.x) {
    int lane = idx & 63, gg = lane >> 4, li = lane & 15;
    int kc = (idx >> 6) & 3;
    int e = 16 * (idx >> 8) + li;
    size_t base = (size_t)lh * 4096 + idx * 4;
    for (int j = 0; j < 4; ++j) {
      int d = 16 * kc + 4 * gg + j;
      float q = 0.f, k = 0.f, v = 0.f;
      if (e < DM) {
        if (d < DM) {
          q = Wq[(size_t)lh * 2401 + d * DM + e] * (1.f / 7.f);
          k = Wk[(size_t)lh * 2401 + d * DM + e];
          v = Wv[(size_t)lh * 2401 + d * DM + e];
        } else if (d == DM) {
          q = bq[lh * DM + e] * (1.f / 7.f);
          k = bk[lh * DM + e];
          v = bv[lh * DM + e];
        }
      }
      QF[base + j] = f2bf(q);
      KF[base + j] = f2bf(k);
      VF[base + j] = f2bf(v);
    }
  }
}

__global__ void prep_comb_frag(const float* __restrict__ Wo, const float* __restrict__ bo,
                               const float* __restrict__ Wcat, const float* __restrict__ bcat,
                               unsigned short* __restrict__ CF) {
  int lh = blockIdx.x, l = lh / NH, hh = lh % NH;
  for (int idx = threadIdx.x; idx < 1024; idx += blockDim.x) {
    int lane = idx & 63, gg = lane >> 4, li = lane & 15;
    int kc = (idx >> 6) & 3;
    int f = 16 * (idx >> 8) + li;
    size_t base = (size_t)lh * 4096 + idx * 4;
    for (int j = 0; j < 4; ++j) {
      int e = 16 * kc + 4 * gg + j;
      float val = 0.f;
      if (f < DM) {
        if (e < DM) {
          for (int c = 0; c < DM; ++c)
            val += Wo[(size_t)lh * 2401 + e * DM + c] *
                   Wcat[((size_t)l * 588 + hh * DM + c) * DM + f];
        } else if (e == DM) {
          for (int c = 0; c < DM; ++c)
            val += bo[lh * DM + c] * Wcat[((size_t)l * 588 + hh * DM + c) * DM + f];
          if (hh == 0) val += bcat[l * DM + f];
        }
      }
      CF[base + j] = f2bf(val);
    }
  }
}

__global__ void prep_ff_frag(const float* __restrict__ W1, const float* __restrict__ b1,
                             const float* __restrict__ W2,
                             unsigned short* __restrict__ W1F, unsigned short* __restrict__ W2F) {
  int l = blockIdx.x;
  // W1F: [64 tiles(j-chunk)][4 kc(d)][64][4]
  for (int idx = threadIdx.x; idx < 16384; idx += blockDim.x) {
    int lane = idx & 63, gg = lane >> 4, li = lane & 15;
    int kc = (idx >> 6) & 3;
    int jcol = 16 * (idx >> 8) + li;
    size_t base = (size_t)l * 65536 + idx * 4;
    for (int j = 0; j < 4; ++j) {
      int d = 16 * kc + 4 * gg + j;
      float v = 0.f;
      if (d < DM) v = W1[(size_t)l * 50176 + d * FFD + jcol];
      else if (d == DM) v = b1[l * FFD + jcol];
      W1F[base + j] = f2bf(v);
    }
  }
  // W2F: [4 ft][64 kt(j-chunk)][64][4]
  for (int idx = threadIdx.x; idx < 16384; idx += blockDim.x) {
    int lane = idx & 63, gg = lane >> 4, li = lane & 15;
    int kt = (idx >> 6) & 63;
    int f = 16 * (idx >> 12) + li;
    size_t base = (size_t)l * 65536 + idx * 4;
    for (int j = 0; j < 4; ++j) {
      int jrow = 16 * kt + 4 * gg + j;
      float v = (f < DM) ? W2[(size_t)l * 50176 + jrow * DM + f] : 0.f;
      W2F[base + j] = f2bf(v);
    }
  }
}

__global__ void prep_small(const float* __restrict__ g1, const float* __restrict__ b1,
                           const float* __restrict__ g2, const float* __restrict__ b2,
                           const float* __restrict__ bff2,
                           float* __restrict__ g1p, float* __restrict__ b1p,
                           float* __restrict__ g2p, float* __restrict__ b2p,
                           float* __restrict__ bff2p) {
  int idx = threadIdx.x;
  if (idx >= 384) return;
  int l = idx >> 6, d = idx & 63;
  bool v = d < DM;
  g1p[idx] = v ? g1[l * DM + d] : 0.f;
  b1p[idx] = v ? b1[l * DM + d] : 0.f;
  g2p[idx] = v ? g2[l * DM + d] : 0.f;
  b2p[idx] = v ? b2[l * DM + d] : 0.f;
  bff2p[idx] = v ? bff2[l * DM + d] : 0.f;
}

// ================= fused transformer: 2 samples/wave, register-resident =================

static __device__ __forceinline__ void ln_pack(const f32x4 (&h)[4], const f32x4 (&gv)[4],
                                               const f32x4 (&bv)[4], int g, u32 (&xn)[4][2]) {
  float s = 0.f, s2 = 0.f;
#pragma unroll
  for (int mi = 0; mi < 4; ++mi)
#pragma unroll
    for (int r = 0; r < 4; ++r) { float v = h[mi][r]; s += v; s2 += v * v; }
  s += __shfl_xor(s, 16, 64); s += __shfl_xor(s, 32, 64);
  s2 += __shfl_xor(s2, 16, 64); s2 += __shfl_xor(s2, 32, 64);
  float mu = s * (1.f / 49.f);
  float rs = rsqrtf(s2 * (1.f / 49.f) - mu * mu + 1e-5f);
#pragma unroll
  for (int mi = 0; mi < 4; ++mi) {
    float xv[4];
#pragma unroll
    for (int r = 0; r < 4; ++r) xv[r] = (h[mi][r] - mu) * rs * gv[mi][r] + bv[mi][r];
    if (mi == 3) xv[1] = (g == 0) ? 1.0f : xv[1];  // bias slot d=49 := 1
    xn[mi][0] = pk2(xv[0], xv[1]);
    xn[mi][1] = pk2(xv[2], xv[3]);
  }
}

static __device__ __forceinline__ void softmax_pk(f32x4 s, u32& p0, u32& p1) {
  float m = fmaxf(fmaxf(s[0], s[1]), fmaxf(s[2], s[3]));
  m = fmaxf(m, __shfl_xor(m, 16, 64));
  m = fmaxf(m, __shfl_xor(m, 32, 64));
  float e0 = __expf(s[0] - m), e1 = __expf(s[1] - m);
  float e2 = __expf(s[2] - m), e3 = __expf(s[3] - m);
  float su = e0 + e1 + e2 + e3;
  su += __shfl_xor(su, 16, 64);
  su += __shfl_xor(su, 32, 64);
  float inv = 1.f / su;
  p0 = pk2(e0 * inv, e1 * inv);
  p1 = pk2(e2 * inv, e3 * inv);
}

__global__ __launch_bounds__(256) void transformer_kernel(
    const float* __restrict__ x, float* __restrict__ out,
    const unsigned short* __restrict__ QF, const unsigned short* __restrict__ KF,
    const unsigned short* __restrict__ VF, const unsigned short* __restrict__ CF,
    const unsigned short* __restrict__ W1F, const unsigned short* __restrict__ W2F,
    const float* __restrict__ lg1, const float* __restrict__ lb1,
    const float* __restrict__ lg2, const float* __restrict__ lb2,
    const float* __restrict__ b2p, const float* __restrict__ Wc,
    const float* __restrict__ bc) {
  const int wv = threadIdx.x >> 6;
  const int lane = threadIdx.x & 63;
  const int g = lane >> 4, li = lane & 15;
  const int s0 = blockIdx.x * 8 + wv * 2;
  const f32x4 z4 = {0.f, 0.f, 0.f, 0.f};

  // h tiles, T-mode: h[mi][r] = h[d = 16mi+4g+r][t = li]
  f32x4 hA[4], hB[4];
  {
    const float* xa = x + (size_t)s0 * 784 + li * DM;
    const float* xb = xa + 784;
#pragma unroll
    for (int mi = 0; mi < 4; ++mi) {
      int d0 = 16 * mi + 4 * g;
#pragma unroll
      for (int r = 0; r < 4; ++r) {
        int d = d0 + r;
        hA[mi][r] = (d < DM) ? xa[d] : 0.f;
        hB[mi][r] = (d < DM) ? xb[d] : 0.f;
      }
    }
  }

  for (int layer = 0; layer < LYR; ++layer) {
    f32x4 g14[4], b14[4], g24[4], b24[4], b2f[4];
#pragma unroll
    for (int mi = 0; mi < 4; ++mi) {
      int off = layer * 64 + 16 * mi + 4 * g;
      g14[mi] = *(const f32x4*)(lg1 + off);
      b14[mi] = *(const f32x4*)(lb1 + off);
      g24[mi] = *(const f32x4*)(lg2 + off);
      b24[mi] = *(const f32x4*)(lb2 + off);
      b2f[mi] = *(const f32x4*)(b2p + off);
    }

    u32 xnA[4][2], xnB[4][2];
    ln_pack(hA, g14, b14, g, xnA);
    ln_pack(hB, g14, b14, g, xnB);

    f32x4 aacA[4], aacB[4];
#pragma unroll
    for (int mi = 0; mi < 4; ++mi) { aacA[mi] = z4; aacB[mi] = z4; }

    for (int hd = 0; hd < NH; ++hd) {
      const int lh = layer * NH + hd;
      const u32x2* qf = (const u32x2*)(QF + (size_t)lh * 4096);
      const u32x2* kf = (const u32x2*)(KF + (size_t)lh * 4096);
      const u32x2* vf = (const u32x2*)(VF + (size_t)lh * 4096);
      const u32x2* cf = (const u32x2*)(CF + (size_t)lh * 4096);

      // q,k (C: rows=e_local, cols=t)
      u32 qA[4][2], qB[4][2], kA[4][2], kB[4][2];
#pragma unroll
      for (int mi = 0; mi < 4; ++mi) {
        f32x4 ca = z4, cb = z4, da = z4, db = z4;
#pragma unroll
        for (int kc = 0; kc < 4; ++kc) {
          u32x2 w = qf[(mi * 4 + kc) * 64 + lane];
          ca = mfma_hz(w.x, w.y, xnA[kc][0], xnA[kc][1], ca);
          cb = mfma_hz(w.x, w.y, xnB[kc][0], xnB[kc][1], cb);
          u32x2 u = kf[(mi * 4 + kc) * 64 + lane];
          da = mfma_hz(u.x, u.y, xnA[kc][0], xnA[kc][1], da);
          db = mfma_hz(u.x, u.y, xnB[kc][0], xnB[kc][1], db);
        }
        qA[mi][0] = pk2(ca[0], ca[1]); qA[mi][1] = pk2(ca[2], ca[3]);
        qB[mi][0] = pk2(cb[0], cb[1]); qB[mi][1] = pk2(cb[2], cb[3]);
        kA[mi][0] = pk2(da[0], da[1]); kA[mi][1] = pk2(da[2], da[3]);
        kB[mi][0] = pk2(db[0], db[1]); kB[mi][1] = pk2(db[2], db[3]);
      }
      // scores (m=s from k, n=t from q) + softmax -> p frags
      u32 pA0, pA1, pB0, pB1;
      {
        f32x4 sa = z4, sb = z4;
#pragma unroll
        for (int mi = 0; mi < 4; ++mi) {
          sa = mfma_hz(kA[mi][0], kA[mi][1], qA[mi][0], qA[mi][1], sa);
          sb = mfma_hz(kB[mi][0], kB[mi][1], qB[mi][0], qB[mi][1], sb);
        }
        softmax_pk(sa, pA0, pA1);
        softmax_pk(sb, pB0, pB1);
      }
      // v (C: rows=t, cols=e) -> fragments with li-space = e
      u32 vA[4][2], vB[4][2];
#pragma unroll
      for (int nt = 0; nt < 4; ++nt) {
        f32x4 ca = z4, cb = z4;
#pragma unroll
        for (int kc = 0; kc < 4; ++kc) {
          u32x2 w = vf[(nt * 4 + kc) * 64 + lane];
          ca = mfma_hz(xnA[kc][0], xnA[kc][1], w.x, w.y, ca);
          cb = mfma_hz(xnB[kc][0], xnB[kc][1], w.x, w.y, cb);
        }
        vA[nt][0] = pk2(ca[0], ca[1]); vA[nt][1] = pk2(ca[2], ca[3]);
        vB[nt][0] = pk2(cb[0], cb[1]); vB[nt][1] = pk2(cb[2], cb[3]);
      }
      // PV (C: rows=e_local, cols=t) -> o frags; inject e=49 bias slot = 1
      u32 oA[4][2], oB[4][2];
#pragma unroll
      for (int nt = 0; nt < 4; ++nt) {
        f32x4 ca = mfma_hz(vA[nt][0], vA[nt][1], pA0, pA1, z4);
        f32x4 cb = mfma_hz(vB[nt][0], vB[nt][1], pB0, pB1, z4);
        if (nt == 3) {
          ca[1] = (g == 0) ? 1.0f : ca[1];
          cb[1] = (g == 0) ? 1.0f : cb[1];
        }
        oA[nt][0] = pk2(ca[0], ca[1]); oA[nt][1] = pk2(ca[2], ca[3]);
        oB[nt][0] = pk2(cb[0], cb[1]); oB[nt][1] = pk2(cb[2], cb[3]);
      }
      // comb: aac[f][t] += o @ (Wo@Wcat)_aug
#pragma unroll
      for (int ft = 0; ft < 4; ++ft) {
#pragma unroll
        for (int nt = 0; nt < 4; ++nt) {
          u32x2 w = cf[(ft * 4 + nt) * 64 + lane];
          aacA[ft] = mfma_hz(w.x, w.y, oA[nt][0], oA[nt][1], aacA[ft]);
          aacB[ft] = mfma_hz(w.x, w.y, oB[nt][0], oB[nt][1], aacB[ft]);
        }
      }
    }

    // x2 = h + attn
#pragma unroll
    for (int mi = 0; mi < 4; ++mi) { hA[mi] += aacA[mi]; hB[mi] += aacB[mi]; }

    // LN2 -> xn2 (reuse xn arrays)
    ln_pack(hA, g24, b24, g, xnA);
    ln_pack(hB, g24, b24, g, xnB);

    // ff acc = x2 + b2
    f32x4 ffA[4], ffB[4];
#pragma unroll
    for (int mi = 0; mi < 4; ++mi) { ffA[mi] = hA[mi] + b2f[mi]; ffB[mi] = hB[mi] + b2f[mi]; }

    const u32x2* w1f = (const u32x2*)(W1F + (size_t)layer * 65536);
    const u32x2* w2f = (const u32x2*)(W2F + (size_t)layer * 65536);
    for (int c = 0; c < 16; ++c) {
      u32 aA[4][2], aB[4][2];
#pragma unroll
      for (int jt = 0; jt < 4; ++jt) {
        f32x4 ca = z4, cb = z4;
#pragma unroll
        for (int kc = 0; kc < 4; ++kc) {
          u32x2 w = w1f[((c * 4 + jt) * 4 + kc) * 64 + lane];
          ca = mfma_hz(w.x, w.y, xnA[kc][0], xnA[kc][1], ca);
          cb = mfma_hz(w.x, w.y, xnB[kc][0], xnB[kc][1], cb);
        }
#pragma unroll
        for (int r = 0; r < 4; ++r) { ca[r] = fmaxf(ca[r], 0.f); cb[r] = fmaxf(cb[r], 0.f); }
        aA[jt][0] = pk2(ca[0], ca[1]); aA[jt][1] = pk2(ca[2], ca[3]);
        aB[jt][0] = pk2(cb[0], cb[1]); aB[jt][1] = pk2(cb[2], cb[3]);
      }
#pragma unroll
      for (int ft = 0; ft < 4; ++ft) {
#pragma unroll
        for (int jt = 0; jt < 4; ++jt) {
          u32x2 w = w2f[(ft * 64 + c * 4 + jt) * 64 + lane];
          ffA[ft] = mfma_hz(w.x, w.y, aA[jt][0], aA[jt][1], ffA[ft]);
          ffB[ft] = mfma_hz(w.x, w.y, aB[jt][0], aB[jt][1], ffB[ft]);
        }
      }
    }
#pragma unroll
    for (int mi = 0; mi < 4; ++mi) { hA[mi] = ffA[mi]; hB[mi] = ffB[mi]; }
  }

  // ---- classification head on token 0 (col li==0) ----
  __shared__ float hs[4][2][64];
  if (li == 0) {
#pragma unroll
    for (int mi = 0; mi < 4; ++mi)
#pragma unroll
      for (int r = 0; r < 4; ++r) {
        hs[wv][0][16 * mi + 4 * g + r] = hA[mi][r];
        hs[wv][1][16 * mi + 4 * g + r] = hB[mi][r];
      }
  }
  __syncthreads();
  if (lane < 20) {
    int smp = lane / 10, c = lane % 10;
    float acc = bc[c];
    const float* hrow = hs[wv][smp];
    for (int d = 0; d < DM; ++d) acc += hrow[d] * Wc[d * NOUT + c];
    out[(size_t)(s0 + smp) * NOUT + c] = acc;
  }
}

extern "C" void kernel_launch(void* const* d_in, const int* in_sizes, int n_in,
                              void* d_out, int out_size, void* d_ws, size_t ws_size,
                              hipStream_t stream) {
  const float* x = (const float*)d_in[0];
  const float* Wq = (const float*)d_in[2];
  const float* bq = (const float*)d_in[3];
  const float* Wk = (const float*)d_in[4];
  const float* bk = (const float*)d_in[5];
  const float* Wv = (const float*)d_in[6];
  const float* bv = (const float*)d_in[7];
  const float* Wo = (const float*)d_in[8];
  const float* bo = (const float*)d_in[9];
  const float* Wcat = (const float*)d_in[10];
  const float* bcat = (const float*)d_in[11];
  const float* ln1_g = (const float*)d_in[12];
  const float* ln1_b = (const float*)d_in[13];
  const float* ln2_g = (const float*)d_in[14];
  const float* ln2_b = (const float*)d_in[15];
  const float* W1 = (const float*)d_in[16];
  const float* b1 = (const float*)d_in[17];
  const float* W2 = (const float*)d_in[18];
  const float* b2 = (const float*)d_in[19];
  const float* Wc = (const float*)d_in[20];
  const float* bc = (const float*)d_in[21];

  unsigned short* QF = (unsigned short*)d_ws;
  unsigned short* KF = QF + (size_t)72 * 4096;
  unsigned short* VF = KF + (size_t)72 * 4096;
  unsigned short* CF = VF + (size_t)72 * 4096;
  unsigned short* W1F = CF + (size_t)72 * 4096;
  unsigned short* W2F = W1F + (size_t)6 * 65536;
  float* fp = (float*)(W2F + (size_t)6 * 65536);
  float* g1p = fp;
  float* b1p = g1p + 384;
  float* g2p = b1p + 384;
  float* b2lp = g2p + 384;
  float* b2p = b2lp + 384;

  prep_qkv_frag<<<72, 256, 0, stream>>>(Wq, bq, Wk, bk, Wv, bv, QF, KF, VF);
  prep_comb_frag<<<72, 256, 0, stream>>>(Wo, bo, Wcat, bcat, CF);
  prep_ff_frag<<<6, 256, 0, stream>>>(W1, b1, W2, W1F, W2F);
  prep_small<<<1, 384, 0, stream>>>(ln1_g, ln1_b, ln2_g, ln2_b, b2, g1p, b1p, g2p, b2lp, b2p);

  transformer_kernel<<<NB / 8, 256, 0, stream>>>(
      x, (float*)d_out, QF, KF, VF, CF, W1F, W2F,
      g1p, b1p, g2p, b2lp, b2p, Wc, bc);
}

// Round 5
// 913.112 us; speedup vs baseline: 8.1767x; 8.1767x over previous
//
#include <hip/hip_runtime.h>

#define LYR 6
#define NH 12
#define DM 49
#define FFD 1024
#define NOUT 10
#define NB 8192
#define NSTG 120  // 6 layers * (12 head-stages + 8 ff-stages), 32 KB each

typedef __bf16 bf16x8 __attribute__((ext_vector_type(8)));
typedef float f32x4 __attribute__((ext_vector_type(4)));
typedef unsigned int u32;
typedef u32 u32x4 __attribute__((ext_vector_type(4)));

static __device__ __forceinline__ f32x4 mfma_full(u32x4 a, u32x4 b, f32x4 c) {
  return __builtin_amdgcn_mfma_f32_16x16x32_bf16(
      __builtin_bit_cast(bf16x8, a), __builtin_bit_cast(bf16x8, b), c, 0, 0, 0);
}

static __device__ __forceinline__ f32x4 mfma_hz(u32 a0, u32 a1, u32 b0, u32 b1, f32x4 c) {
  u32x4 A = {a0, a1, 0u, 0u};
  u32x4 B = {b0, b1, 0u, 0u};
  return mfma_full(A, B, c);
}

static __device__ __forceinline__ unsigned short f2bf(float f) {
  union { float f; unsigned u; } c; c.f = f;
  unsigned r = c.u + 0x7fffu + ((c.u >> 16) & 1u);
  return (unsigned short)(r >> 16);
}

static __device__ __forceinline__ u32 pk2(float a, float b) {
  return (u32)f2bf(a) | ((u32)f2bf(b) << 16);
}

// ============ fragment-linear section decode ============
// section = 4096 ushorts: idx = ((tile*2+ks)*64+lane)*8 + j
// col = 16*tile + (lane&15);  k-slot d = 16*(2*ks + (j>=4)) + 4*(lane>>4) + (j&3)
static __device__ __forceinline__ void decode(int idx, int& d, int& col) {
  int tile = idx >> 10, ks = (idx >> 9) & 1, lane = (idx >> 3) & 63, j = idx & 7;
  col = 16 * tile + (lane & 15);
  d = 16 * (2 * ks + (j >= 4 ? 1 : 0)) + 4 * (lane >> 4) + (j & 3);
}

// blob layout: stage s (16384 ushorts each), s = l*20 + w
//   w in [0,12): head block: [QF 4096][KF 4096][VF 4096][CF 4096]
//   w in [12,20): ff block fb: [c_rel0: W1F 4096 | W2F 4096][c_rel1: ...], c = 2*fb+c_rel

__global__ void prep_qkv_frag(const float* __restrict__ Wq, const float* __restrict__ bq,
                              const float* __restrict__ Wk, const float* __restrict__ bk,
                              const float* __restrict__ Wv, const float* __restrict__ bv,
                              unsigned short* __restrict__ blob) {
  int lh = blockIdx.x, l = lh / NH, hd = lh % NH;
  unsigned short* base = blob + (size_t)(l * 20 + hd) * 16384;
  for (int idx = threadIdx.x; idx < 4096; idx += blockDim.x) {
    int d, e;
    decode(idx, d, e);
    float q = 0.f, k = 0.f, v = 0.f;
    if (e < DM) {
      if (d < DM) {
        q = Wq[(size_t)lh * 2401 + d * DM + e] * (1.f / 7.f);
        k = Wk[(size_t)lh * 2401 + d * DM + e];
        v = Wv[(size_t)lh * 2401 + d * DM + e];
      } else if (d == DM) {
        q = bq[lh * DM + e] * (1.f / 7.f);
        k = bk[lh * DM + e];
        v = bv[lh * DM + e];
      }
    }
    base[idx] = f2bf(q);
    base[4096 + idx] = f2bf(k);
    base[8192 + idx] = f2bf(v);
  }
}

__global__ void prep_comb_frag(const float* __restrict__ Wo, const float* __restrict__ bo,
                               const float* __restrict__ Wcat, const float* __restrict__ bcat,
                               unsigned short* __restrict__ blob) {
  int lh = blockIdx.x, l = lh / NH, hh = lh % NH;
  unsigned short* base = blob + (size_t)(l * 20 + hh) * 16384 + 12288;
  for (int idx = threadIdx.x; idx < 4096; idx += blockDim.x) {
    int e, f;
    decode(idx, e, f);
    float val = 0.f;
    if (f < DM) {
      if (e < DM) {
        for (int c = 0; c < DM; ++c)
          val += Wo[(size_t)lh * 2401 + e * DM + c] *
                 Wcat[((size_t)l * 588 + hh * DM + c) * DM + f];
      } else if (e == DM) {
        for (int c = 0; c < DM; ++c)
          val += bo[lh * DM + c] * Wcat[((size_t)l * 588 + hh * DM + c) * DM + f];
        if (hh == 0) val += bcat[l * DM + f];
      }
    }
    base[idx] = f2bf(val);
  }
}

__global__ void prep_ff_frag(const float* __restrict__ W1, const float* __restrict__ b1,
                             const float* __restrict__ W2,
                             unsigned short* __restrict__ blob) {
  int l = blockIdx.x;
  for (int idx = threadIdx.x; idx < 131072; idx += blockDim.x) {
    int c = idx >> 13, within = idx & 8191, sec = within >> 12, sidx = within & 4095;
    int fb = c >> 1, c_rel = c & 1;
    unsigned short* dst =
        blob + (size_t)(l * 20 + 12 + fb) * 16384 + c_rel * 8192 + sec * 4096;
    int d, col;
    decode(sidx, d, col);
    float v = 0.f;
    if (sec == 0) {  // W1: rows j (col-space), k = d_aug
      int jcol = 64 * c + col;
      if (d < DM) v = W1[(size_t)l * DM * FFD + d * FFD + jcol];
      else if (d == DM) v = b1[l * FFD + jcol];
    } else {  // W2: rows f (col-space), k = j within chunk
      int jg = 64 * c + d;
      if (col < DM) v = W2[(size_t)l * FFD * DM + jg * DM + col];
    }
    dst[sidx] = f2bf(v);
  }
}

__global__ void prep_small(const float* __restrict__ g1, const float* __restrict__ b1,
                           const float* __restrict__ g2, const float* __restrict__ b2,
                           const float* __restrict__ bff2,
                           float* __restrict__ g1p, float* __restrict__ b1p,
                           float* __restrict__ g2p, float* __restrict__ b2p,
                           float* __restrict__ bff2p) {
  int idx = threadIdx.x;
  if (idx >= 384) return;
  int l = idx >> 6, d = idx & 63;
  bool v = d < DM;
  g1p[idx] = v ? g1[l * DM + d] : 0.f;
  b1p[idx] = v ? b1[l * DM + d] : 0.f;
  g2p[idx] = v ? g2[l * DM + d] : 0.f;
  b2p[idx] = v ? b2[l * DM + d] : 0.f;
  bff2p[idx] = v ? bff2[l * DM + d] : 0.f;
}

// ================= fused transformer =================

static __device__ __forceinline__ void ln_pack(const f32x4 (&h)[4], const f32x4 (&gv)[4],
                                               const f32x4 (&bv)[4], int g, u32 (&xn)[4][2]) {
  float s = 0.f, s2 = 0.f;
#pragma unroll
  for (int mi = 0; mi < 4; ++mi)
#pragma unroll
    for (int r = 0; r < 4; ++r) { float v = h[mi][r]; s += v; s2 += v * v; }
  s += __shfl_xor(s, 16, 64); s += __shfl_xor(s, 32, 64);
  s2 += __shfl_xor(s2, 16, 64); s2 += __shfl_xor(s2, 32, 64);
  float mu = s * (1.f / 49.f);
  float rs = rsqrtf(s2 * (1.f / 49.f) - mu * mu + 1e-5f);
#pragma unroll
  for (int mi = 0; mi < 4; ++mi) {
    float xv[4];
#pragma unroll
    for (int r = 0; r < 4; ++r) xv[r] = (h[mi][r] - mu) * rs * gv[mi][r] + bv[mi][r];
    if (mi == 3) xv[1] = (g == 0) ? 1.0f : xv[1];  // bias slot d=49 := 1
    xn[mi][0] = pk2(xv[0], xv[1]);
    xn[mi][1] = pk2(xv[2], xv[3]);
  }
}

static __device__ __forceinline__ void softmax_pk(f32x4 s, u32& p0, u32& p1) {
  float m = fmaxf(fmaxf(s[0], s[1]), fmaxf(s[2], s[3]));
  m = fmaxf(m, __shfl_xor(m, 16, 64));
  m = fmaxf(m, __shfl_xor(m, 32, 64));
  float e0 = __expf(s[0] - m), e1 = __expf(s[1] - m);
  float e2 = __expf(s[2] - m), e3 = __expf(s[3] - m);
  float su = e0 + e1 + e2 + e3;
  su += __shfl_xor(su, 16, 64);
  su += __shfl_xor(su, 32, 64);
  float inv = 1.f / su;
  p0 = pk2(e0 * inv, e1 * inv);
  p1 = pk2(e2 * inv, e3 * inv);
}

// commit prefetched regs -> LDS buf, barrier, then issue next stage's loads
#define STAGE_COMMIT()                                                        \
  do {                                                                        \
    u32x4* lb = (u32x4*)wbuf[stage & 1];                                      \
    _Pragma("unroll") for (int r = 0; r < 8; ++r) lb[r * 256 + tid] = stg[r]; \
    __syncthreads();                                                          \
    if (stage + 1 < NSTG) {                                                   \
      const u32x4* gs = (const u32x4*)(blob + (size_t)(stage + 1) * 16384);   \
      _Pragma("unroll") for (int r = 0; r < 8; ++r) stg[r] = gs[r * 256 + tid]; \
    }                                                                         \
  } while (0)

__global__ __launch_bounds__(256, 2) void transformer_kernel(
    const float* __restrict__ x, float* __restrict__ out,
    const unsigned short* __restrict__ blob,
    const float* __restrict__ lg1, const float* __restrict__ lb1,
    const float* __restrict__ lg2, const float* __restrict__ lb2,
    const float* __restrict__ b2p, const float* __restrict__ Wc,
    const float* __restrict__ bc) {
  __shared__ __align__(16) unsigned short wbuf[2][16384];
  const int tid = threadIdx.x;
  const int wv = tid >> 6, lane = tid & 63;
  const int g = lane >> 4, li = lane & 15;
  const int s0 = blockIdx.x * 8 + wv * 2;
  const f32x4 z4 = {0.f, 0.f, 0.f, 0.f};

  // prologue: prefetch stage 0 into regs
  u32x4 stg[8];
  {
    const u32x4* gs = (const u32x4*)blob;
#pragma unroll
    for (int r = 0; r < 8; ++r) stg[r] = gs[r * 256 + tid];
  }

  // h tiles: h[mi][r] = h[d=16mi+4g+r][t=li]
  f32x4 hA[4], hB[4];
  {
    const float* xa = x + (size_t)s0 * 784 + li * DM;
    const float* xb = xa + 784;
#pragma unroll
    for (int mi = 0; mi < 4; ++mi) {
      int d0 = 16 * mi + 4 * g;
#pragma unroll
      for (int r = 0; r < 4; ++r) {
        int d = d0 + r;
        hA[mi][r] = (d < DM) ? xa[d] : 0.f;
        hB[mi][r] = (d < DM) ? xb[d] : 0.f;
      }
    }
  }

  int stage = 0;
  for (int layer = 0; layer < LYR; ++layer) {
    f32x4 g14[4], b14[4], g24[4], b24[4], b2f[4];
#pragma unroll
    for (int mi = 0; mi < 4; ++mi) {
      int off = layer * 64 + 16 * mi + 4 * g;
      g14[mi] = *(const f32x4*)(lg1 + off);
      b14[mi] = *(const f32x4*)(lb1 + off);
      g24[mi] = *(const f32x4*)(lg2 + off);
      b24[mi] = *(const f32x4*)(lb2 + off);
      b2f[mi] = *(const f32x4*)(b2p + off);
    }

    u32 xnA[4][2], xnB[4][2];
    ln_pack(hA, g14, b14, g, xnA);
    ln_pack(hB, g14, b14, g, xnB);
    u32x4 xfA[2], xfB[2];
    xfA[0] = u32x4{xnA[0][0], xnA[0][1], xnA[1][0], xnA[1][1]};
    xfA[1] = u32x4{xnA[2][0], xnA[2][1], xnA[3][0], xnA[3][1]};
    xfB[0] = u32x4{xnB[0][0], xnB[0][1], xnB[1][0], xnB[1][1]};
    xfB[1] = u32x4{xnB[2][0], xnB[2][1], xnB[3][0], xnB[3][1]};

    f32x4 aacA[4], aacB[4];
#pragma unroll
    for (int mi = 0; mi < 4; ++mi) { aacA[mi] = z4; aacB[mi] = z4; }

    for (int hd = 0; hd < NH; ++hd) {
      STAGE_COMMIT();
      const unsigned short* W = wbuf[stage & 1];
      ++stage;
      const u32x4* QW = (const u32x4*)W;
      const u32x4* KW = (const u32x4*)(W + 4096);
      const u32x4* VW = (const u32x4*)(W + 8192);
      const u32x4* CW = (const u32x4*)(W + 12288);

      // q,k (C: rows=e_local, cols=t)
      u32 qA[4][2], qB[4][2], kA[4][2], kB[4][2];
#pragma unroll
      for (int mi = 0; mi < 4; ++mi) {
        f32x4 ca = z4, cb = z4, da = z4, db = z4;
#pragma unroll
        for (int ks = 0; ks < 2; ++ks) {
          u32x4 wq = QW[(mi * 2 + ks) * 64 + lane];
          ca = mfma_full(wq, xfA[ks], ca);
          cb = mfma_full(wq, xfB[ks], cb);
          u32x4 wk = KW[(mi * 2 + ks) * 64 + lane];
          da = mfma_full(wk, xfA[ks], da);
          db = mfma_full(wk, xfB[ks], db);
        }
        qA[mi][0] = pk2(ca[0], ca[1]); qA[mi][1] = pk2(ca[2], ca[3]);
        qB[mi][0] = pk2(cb[0], cb[1]); qB[mi][1] = pk2(cb[2], cb[3]);
        kA[mi][0] = pk2(da[0], da[1]); kA[mi][1] = pk2(da[2], da[3]);
        kB[mi][0] = pk2(db[0], db[1]); kB[mi][1] = pk2(db[2], db[3]);
      }
      // scores + softmax -> p frags
      u32 pA0, pA1, pB0, pB1;
      {
        u32x4 kf0 = {kA[0][0], kA[0][1], kA[1][0], kA[1][1]};
        u32x4 kf1 = {kA[2][0], kA[2][1], kA[3][0], kA[3][1]};
        u32x4 qf0 = {qA[0][0], qA[0][1], qA[1][0], qA[1][1]};
        u32x4 qf1 = {qA[2][0], qA[2][1], qA[3][0], qA[3][1]};
        f32x4 sa = mfma_full(kf0, qf0, z4);
        sa = mfma_full(kf1, qf1, sa);
        u32x4 kg0 = {kB[0][0], kB[0][1], kB[1][0], kB[1][1]};
        u32x4 kg1 = {kB[2][0], kB[2][1], kB[3][0], kB[3][1]};
        u32x4 qg0 = {qB[0][0], qB[0][1], qB[1][0], qB[1][1]};
        u32x4 qg1 = {qB[2][0], qB[2][1], qB[3][0], qB[3][1]};
        f32x4 sb = mfma_full(kg0, qg0, z4);
        sb = mfma_full(kg1, qg1, sb);
        softmax_pk(sa, pA0, pA1);
        softmax_pk(sb, pB0, pB1);
      }
      // v (C: rows=t, cols=e)
      u32 vA[4][2], vB[4][2];
#pragma unroll
      for (int nt = 0; nt < 4; ++nt) {
        f32x4 ca = z4, cb = z4;
#pragma unroll
        for (int ks = 0; ks < 2; ++ks) {
          u32x4 w = VW[(nt * 2 + ks) * 64 + lane];
          ca = mfma_full(xfA[ks], w, ca);
          cb = mfma_full(xfB[ks], w, cb);
        }
        vA[nt][0] = pk2(ca[0], ca[1]); vA[nt][1] = pk2(ca[2], ca[3]);
        vB[nt][0] = pk2(cb[0], cb[1]); vB[nt][1] = pk2(cb[2], cb[3]);
      }
      // PV (K=16): C rows=e_local, cols=t; inject e=49 bias slot = 1
      u32 oA[4][2], oB[4][2];
#pragma unroll
      for (int nt = 0; nt < 4; ++nt) {
        f32x4 ca = mfma_hz(vA[nt][0], vA[nt][1], pA0, pA1, z4);
        f32x4 cb = mfma_hz(vB[nt][0], vB[nt][1], pB0, pB1, z4);
        if (nt == 3) {
          ca[1] = (g == 0) ? 1.0f : ca[1];
          cb[1] = (g == 0) ? 1.0f : cb[1];
        }
        oA[nt][0] = pk2(ca[0], ca[1]); oA[nt][1] = pk2(ca[2], ca[3]);
        oB[nt][0] = pk2(cb[0], cb[1]); oB[nt][1] = pk2(cb[2], cb[3]);
      }
      // comb: aac[f][t] += (Wo@Wcat)_aug^T @ o
      u32x4 ofA0 = {oA[0][0], oA[0][1], oA[1][0], oA[1][1]};
      u32x4 ofA1 = {oA[2][0], oA[2][1], oA[3][0], oA[3][1]};
      u32x4 ofB0 = {oB[0][0], oB[0][1], oB[1][0], oB[1][1]};
      u32x4 ofB1 = {oB[2][0], oB[2][1], oB[3][0], oB[3][1]};
#pragma unroll
      for (int ft = 0; ft < 4; ++ft) {
        u32x4 w0 = CW[(ft * 2 + 0) * 64 + lane];
        aacA[ft] = mfma_full(w0, ofA0, aacA[ft]);
        aacB[ft] = mfma_full(w0, ofB0, aacB[ft]);
        u32x4 w1 = CW[(ft * 2 + 1) * 64 + lane];
        aacA[ft] = mfma_full(w1, ofA1, aacA[ft]);
        aacB[ft] = mfma_full(w1, ofB1, aacB[ft]);
      }
    }

    // x2 = h + attn
#pragma unroll
    for (int mi = 0; mi < 4; ++mi) { hA[mi] += aacA[mi]; hB[mi] += aacB[mi]; }

    // LN2
    ln_pack(hA, g24, b24, g, xnA);
    ln_pack(hB, g24, b24, g, xnB);
    u32x4 xf2A[2], xf2B[2];
    xf2A[0] = u32x4{xnA[0][0], xnA[0][1], xnA[1][0], xnA[1][1]};
    xf2A[1] = u32x4{xnA[2][0], xnA[2][1], xnA[3][0], xnA[3][1]};
    xf2B[0] = u32x4{xnB[0][0], xnB[0][1], xnB[1][0], xnB[1][1]};
    xf2B[1] = u32x4{xnB[2][0], xnB[2][1], xnB[3][0], xnB[3][1]};

    // ff acc = x2 + b2
    f32x4 ffA[4], ffB[4];
#pragma unroll
    for (int mi = 0; mi < 4; ++mi) { ffA[mi] = hA[mi] + b2f[mi]; ffB[mi] = hB[mi] + b2f[mi]; }

    for (int fb = 0; fb < 8; ++fb) {
      STAGE_COMMIT();
      const unsigned short* W = wbuf[stage & 1];
      ++stage;
#pragma unroll
      for (int cr = 0; cr < 2; ++cr) {
        const u32x4* W1c = (const u32x4*)(W + cr * 8192);
        const u32x4* W2c = (const u32x4*)(W + cr * 8192 + 4096);
        u32 aA[4][2], aB[4][2];
#pragma unroll
        for (int jt = 0; jt < 4; ++jt) {
          f32x4 ca = z4, cb = z4;
#pragma unroll
          for (int ks = 0; ks < 2; ++ks) {
            u32x4 w = W1c[(jt * 2 + ks) * 64 + lane];
            ca = mfma_full(w, xf2A[ks], ca);
            cb = mfma_full(w, xf2B[ks], cb);
          }
#pragma unroll
          for (int r = 0; r < 4; ++r) { ca[r] = fmaxf(ca[r], 0.f); cb[r] = fmaxf(cb[r], 0.f); }
          aA[jt][0] = pk2(ca[0], ca[1]); aA[jt][1] = pk2(ca[2], ca[3]);
          aB[jt][0] = pk2(cb[0], cb[1]); aB[jt][1] = pk2(cb[2], cb[3]);
        }
        u32x4 afA0 = {aA[0][0], aA[0][1], aA[1][0], aA[1][1]};
        u32x4 afA1 = {aA[2][0], aA[2][1], aA[3][0], aA[3][1]};
        u32x4 afB0 = {aB[0][0], aB[0][1], aB[1][0], aB[1][1]};
        u32x4 afB1 = {aB[2][0], aB[2][1], aB[3][0], aB[3][1]};
#pragma unroll
        for (int ft = 0; ft < 4; ++ft) {
          u32x4 w0 = W2c[(ft * 2 + 0) * 64 + lane];
          ffA[ft] = mfma_full(w0, afA0, ffA[ft]);
          ffB[ft] = mfma_full(w0, afB0, ffB[ft]);
          u32x4 w1 = W2c[(ft * 2 + 1) * 64 + lane];
          ffA[ft] = mfma_full(w1, afA1, ffA[ft]);
          ffB[ft] = mfma_full(w1, afB1, ffB[ft]);
        }
      }
    }
#pragma unroll
    for (int mi = 0; mi < 4; ++mi) { hA[mi] = ffA[mi]; hB[mi] = ffB[mi]; }
  }

  // ---- classification head on token 0 (col li==0); overlay scratch on wbuf ----
  __syncthreads();
  float* hs = (float*)&wbuf[0][0];  // [4 waves][2 samples][64]
  if (li == 0) {
#pragma unroll
    for (int mi = 0; mi < 4; ++mi)
#pragma unroll
      for (int r = 0; r < 4; ++r) {
        hs[(wv * 2 + 0) * 64 + 16 * mi + 4 * g + r] = hA[mi][r];
        hs[(wv * 2 + 1) * 64 + 16 * mi + 4 * g + r] = hB[mi][r];
      }
  }
  __syncthreads();
  if (lane < 20) {
    int smp = lane / 10, c = lane % 10;
    float acc = bc[c];
    const float* hrow = hs + (wv * 2 + smp) * 64;
    for (int d = 0; d < DM; ++d) acc += hrow[d] * Wc[d * NOUT + c];
    out[(size_t)(s0 + smp) * NOUT + c] = acc;
  }
}

extern "C" void kernel_launch(void* const* d_in, const int* in_sizes, int n_in,
                              void* d_out, int out_size, void* d_ws, size_t ws_size,
                              hipStream_t stream) {
  const float* x = (const float*)d_in[0];
  const float* Wq = (const float*)d_in[2];
  const float* bq = (const float*)d_in[3];
  const float* Wk = (const float*)d_in[4];
  const float* bk = (const float*)d_in[5];
  const float* Wv = (const float*)d_in[6];
  const float* bv = (const float*)d_in[7];
  const float* Wo = (const float*)d_in[8];
  const float* bo = (const float*)d_in[9];
  const float* Wcat = (const float*)d_in[10];
  const float* bcat = (const float*)d_in[11];
  const float* ln1_g = (const float*)d_in[12];
  const float* ln1_b = (const float*)d_in[13];
  const float* ln2_g = (const float*)d_in[14];
  const float* ln2_b = (const float*)d_in[15];
  const float* W1 = (const float*)d_in[16];
  const float* b1 = (const float*)d_in[17];
  const float* W2 = (const float*)d_in[18];
  const float* b2 = (const float*)d_in[19];
  const float* Wc = (const float*)d_in[20];
  const float* bc = (const float*)d_in[21];

  unsigned short* blob = (unsigned short*)d_ws;  // NSTG * 16384 ushorts
  float* fp = (float*)(blob + (size_t)NSTG * 16384);
  float* g1p = fp;
  float* b1p = g1p + 384;
  float* g2p = b1p + 384;
  float* b2lp = g2p + 384;
  float* b2p = b2lp + 384;

  prep_qkv_frag<<<72, 256, 0, stream>>>(Wq, bq, Wk, bk, Wv, bv, blob);
  prep_comb_frag<<<72, 256, 0, stream>>>(Wo, bo, Wcat, bcat, blob);
  prep_ff_frag<<<6, 256, 0, stream>>>(W1, b1, W2, blob);
  prep_small<<<1, 384, 0, stream>>>(ln1_g, ln1_b, ln2_g, ln2_b, b2, g1p, b1p, g2p, b2lp, b2p);

  transformer_kernel<<<NB / 8, 256, 0, stream>>>(
      x, (float*)d_out, blob, g1p, b1p, g2p, b2lp, b2p, Wc, bc);
}

// Round 6
// 615.467 us; speedup vs baseline: 12.1310x; 1.4836x over previous
//
#include <hip/hip_runtime.h>
#include <hip/hip_bf16.h>

#define LYR 6
#define NH 12
#define DM 49
#define FFD 1024
#define NOUT 10
#define NB 8192
#define NSTG 120  // 6 layers * (12 head-stages + 8 ff-stages), 32 KB each

typedef __bf16 bf16x8 __attribute__((ext_vector_type(8)));
typedef float f32x4 __attribute__((ext_vector_type(4)));
typedef unsigned int u32;
typedef u32 u32x4 __attribute__((ext_vector_type(4)));

static __device__ __forceinline__ f32x4 mfma_full(u32x4 a, u32x4 b, f32x4 c) {
  return __builtin_amdgcn_mfma_f32_16x16x32_bf16(
      __builtin_bit_cast(bf16x8, a), __builtin_bit_cast(bf16x8, b), c, 0, 0, 0);
}

static __device__ __forceinline__ f32x4 mfma_hz(u32 a0, u32 a1, u32 b0, u32 b1, f32x4 c) {
  u32x4 A = {a0, a1, 0u, 0u};
  u32x4 B = {b0, b1, 0u, 0u};
  return mfma_full(A, B, c);
}

static __device__ __forceinline__ unsigned short f2bf(float f) {
  union { float f; unsigned u; } c; c.f = f;
  unsigned r = c.u + 0x7fffu + ((c.u >> 16) & 1u);
  return (unsigned short)(r >> 16);
}

// packed f32x2 -> bf16x2 ; lowers to v_cvt_pk_bf16_f32 (RNE, same as f2bf)
static __device__ __forceinline__ u32 pk2(float a, float b) {
  __hip_bfloat162 h2 = __float22bfloat162_rn(make_float2(a, b));
  u32 r;
  __builtin_memcpy(&r, &h2, 4);
  return r;
}

// direct global->LDS copy, 16B per lane; lds dest must be wave-uniform base
static __device__ __forceinline__ void gload16(const void* gp, void* lp) {
  __builtin_amdgcn_global_load_lds(
      (const __attribute__((address_space(1))) unsigned int*)gp,
      (__attribute__((address_space(3))) unsigned int*)lp, 16, 0, 0);
}

// ============ fragment-linear section decode ============
// section = 4096 ushorts: idx = ((tile*2+ks)*64+lane)*8 + j
// col = 16*tile + (lane&15);  k-slot d = 16*(2*ks + (j>=4)) + 4*(lane>>4) + (j&3)
static __device__ __forceinline__ void decode(int idx, int& d, int& col) {
  int tile = idx >> 10, ks = (idx >> 9) & 1, lane = (idx >> 3) & 63, j = idx & 7;
  col = 16 * tile + (lane & 15);
  d = 16 * (2 * ks + (j >= 4 ? 1 : 0)) + 4 * (lane >> 4) + (j & 3);
}

// blob layout: stage s (16384 ushorts each), s = l*20 + w
//   w in [0,12): head block: [QF 4096][KF 4096][VF 4096][CF 4096]
//   w in [12,20): ff block fb: [c_rel0: W1F 4096 | W2F 4096][c_rel1: ...], c = 2*fb+c_rel

__global__ void prep_qkv_frag(const float* __restrict__ Wq, const float* __restrict__ bq,
                              const float* __restrict__ Wk, const float* __restrict__ bk,
                              const float* __restrict__ Wv, const float* __restrict__ bv,
                              unsigned short* __restrict__ blob) {
  int lh = blockIdx.x, l = lh / NH, hd = lh % NH;
  unsigned short* base = blob + (size_t)(l * 20 + hd) * 16384;
  for (int idx = threadIdx.x; idx < 4096; idx += blockDim.x) {
    int d, e;
    decode(idx, d, e);
    float q = 0.f, k = 0.f, v = 0.f;
    if (e < DM) {
      if (d < DM) {
        q = Wq[(size_t)lh * 2401 + d * DM + e] * (1.f / 7.f);
        k = Wk[(size_t)lh * 2401 + d * DM + e];
        v = Wv[(size_t)lh * 2401 + d * DM + e];
      } else if (d == DM) {
        q = bq[lh * DM + e] * (1.f / 7.f);
        k = bk[lh * DM + e];
        v = bv[lh * DM + e];
      }
    }
    base[idx] = f2bf(q);
    base[4096 + idx] = f2bf(k);
    base[8192 + idx] = f2bf(v);
  }
}

__global__ void prep_comb_frag(const float* __restrict__ Wo, const float* __restrict__ bo,
                               const float* __restrict__ Wcat, const float* __restrict__ bcat,
                               unsigned short* __restrict__ blob) {
  int lh = blockIdx.x, l = lh / NH, hh = lh % NH;
  unsigned short* base = blob + (size_t)(l * 20 + hh) * 16384 + 12288;
  for (int idx = threadIdx.x; idx < 4096; idx += blockDim.x) {
    int e, f;
    decode(idx, e, f);
    float val = 0.f;
    if (f < DM) {
      if (e < DM) {
        for (int c = 0; c < DM; ++c)
          val += Wo[(size_t)lh * 2401 + e * DM + c] *
                 Wcat[((size_t)l * 588 + hh * DM + c) * DM + f];
      } else if (e == DM) {
        for (int c = 0; c < DM; ++c)
          val += bo[lh * DM + c] * Wcat[((size_t)l * 588 + hh * DM + c) * DM + f];
        if (hh == 0) val += bcat[l * DM + f];
      }
    }
    base[idx] = f2bf(val);
  }
}

__global__ void prep_ff_frag(const float* __restrict__ W1, const float* __restrict__ b1,
                             const float* __restrict__ W2,
                             unsigned short* __restrict__ blob) {
  int l = blockIdx.x >> 3, part = blockIdx.x & 7;
  for (int idx = part * 16384 + threadIdx.x; idx < (part + 1) * 16384; idx += blockDim.x) {
    int c = idx >> 13, within = idx & 8191, sec = within >> 12, sidx = within & 4095;
    int fb = c >> 1, c_rel = c & 1;
    unsigned short* dst =
        blob + (size_t)(l * 20 + 12 + fb) * 16384 + c_rel * 8192 + sec * 4096;
    int d, col;
    decode(sidx, d, col);
    float v = 0.f;
    if (sec == 0) {  // W1: cols j, k = d_aug
      int jcol = 64 * c + col;
      if (d < DM) v = W1[(size_t)l * DM * FFD + d * FFD + jcol];
      else if (d == DM) v = b1[l * FFD + jcol];
    } else {  // W2: cols f, k = j within chunk
      int jg = 64 * c + d;
      if (col < DM) v = W2[(size_t)l * FFD * DM + jg * DM + col];
    }
    dst[sidx] = f2bf(v);
  }
}

__global__ void prep_small(const float* __restrict__ g1, const float* __restrict__ b1,
                           const float* __restrict__ g2, const float* __restrict__ b2,
                           const float* __restrict__ bff2,
                           float* __restrict__ g1p, float* __restrict__ b1p,
                           float* __restrict__ g2p, float* __restrict__ b2p,
                           float* __restrict__ bff2p) {
  int idx = threadIdx.x;
  if (idx >= 384) return;
  int l = idx >> 6, d = idx & 63;
  bool v = d < DM;
  g1p[idx] = v ? g1[l * DM + d] : 0.f;
  b1p[idx] = v ? b1[l * DM + d] : 0.f;
  g2p[idx] = v ? g2[l * DM + d] : 0.f;
  b2p[idx] = v ? b2[l * DM + d] : 0.f;
  bff2p[idx] = v ? bff2[l * DM + d] : 0.f;
}

// ================= fused transformer: 4 samples/wave =================

static __device__ __forceinline__ void ln_pack(const f32x4 (&h)[4], const f32x4 (&gv)[4],
                                               const f32x4 (&bv)[4], int g, u32x4 (&xf)[2]) {
  float s = 0.f, s2 = 0.f;
#pragma unroll
  for (int mi = 0; mi < 4; ++mi)
#pragma unroll
    for (int r = 0; r < 4; ++r) { float v = h[mi][r]; s += v; s2 += v * v; }
  s += __shfl_xor(s, 16, 64); s += __shfl_xor(s, 32, 64);
  s2 += __shfl_xor(s2, 16, 64); s2 += __shfl_xor(s2, 32, 64);
  float mu = s * (1.f / 49.f);
  float rs = rsqrtf(s2 * (1.f / 49.f) - mu * mu + 1e-5f);
  u32 t[8];
#pragma unroll
  for (int mi = 0; mi < 4; ++mi) {
    float xv[4];
#pragma unroll
    for (int r = 0; r < 4; ++r) xv[r] = (h[mi][r] - mu) * rs * gv[mi][r] + bv[mi][r];
    if (mi == 3) xv[1] = (g == 0) ? 1.0f : xv[1];  // bias slot d=49 := 1
    t[2 * mi] = pk2(xv[0], xv[1]);
    t[2 * mi + 1] = pk2(xv[2], xv[3]);
  }
  xf[0] = u32x4{t[0], t[1], t[2], t[3]};
  xf[1] = u32x4{t[4], t[5], t[6], t[7]};
}

static __device__ __forceinline__ void softmax_pk(f32x4 s, u32& p0, u32& p1) {
  float m = fmaxf(fmaxf(s[0], s[1]), fmaxf(s[2], s[3]));
  m = fmaxf(m, __shfl_xor(m, 16, 64));
  m = fmaxf(m, __shfl_xor(m, 32, 64));
  float e0 = __expf(s[0] - m), e1 = __expf(s[1] - m);
  float e2 = __expf(s[2] - m), e3 = __expf(s[3] - m);
  float su = e0 + e1 + e2 + e3;
  su += __shfl_xor(su, 16, 64);
  su += __shfl_xor(su, 32, 64);
  float inv = 1.f / su;
  p0 = pk2(e0 * inv, e1 * inv);
  p1 = pk2(e2 * inv, e3 * inv);
}

// issue next stage's loads: per-lane global src, wave-uniform LDS dest + lane*16
#define STAGE_LOAD(s)                                                         \
  do {                                                                        \
    const unsigned short* gsrc = blob + (size_t)(s) * 16384 + tid * 8;        \
    unsigned short* ldst = &wbuf[(s) & 1][wv * 512];                          \
    _Pragma("unroll") for (int r = 0; r < 8; ++r)                             \
        gload16(gsrc + r * 2048, ldst + r * 2048);                            \
  } while (0)

__global__ __launch_bounds__(256, 2) void transformer_kernel(
    const float* __restrict__ x, float* __restrict__ out,
    const unsigned short* __restrict__ blob,
    const float* __restrict__ lg1, const float* __restrict__ lb1,
    const float* __restrict__ lg2, const float* __restrict__ lb2,
    const float* __restrict__ b2p, const float* __restrict__ Wc,
    const float* __restrict__ bc) {
  __shared__ __align__(16) unsigned short wbuf[2][16384];
  const int tid = threadIdx.x;
  const int wv = tid >> 6, lane = tid & 63;
  const int g = lane >> 4, li = lane & 15;
  const int s0 = blockIdx.x * 16 + wv * 4;
  const f32x4 z4 = {0.f, 0.f, 0.f, 0.f};

  STAGE_LOAD(0);

  // h tiles: h[s][mi][r] = h[d=16mi+4g+r][t=li] for sample s0+s
  f32x4 h[4][4];
#pragma unroll
  for (int s = 0; s < 4; ++s) {
    const float* xa = x + (size_t)(s0 + s) * 784 + li * DM;
#pragma unroll
    for (int mi = 0; mi < 4; ++mi)
#pragma unroll
      for (int r = 0; r < 4; ++r) {
        int d = 16 * mi + 4 * g + r;
        h[s][mi][r] = (d < DM) ? xa[d] : 0.f;
      }
  }

  int stage = 0;
  for (int layer = 0; layer < LYR; ++layer) {
    u32x4 xf[4][2];
    {
      f32x4 gv[4], bv[4];
#pragma unroll
      for (int mi = 0; mi < 4; ++mi) {
        int off = layer * 64 + 16 * mi + 4 * g;
        gv[mi] = *(const f32x4*)(lg1 + off);
        bv[mi] = *(const f32x4*)(lb1 + off);
      }
#pragma unroll
      for (int s = 0; s < 4; ++s) ln_pack(h[s], gv, bv, g, xf[s]);
    }

    for (int hd = 0; hd < NH; ++hd) {
      __syncthreads();  // implicit vmcnt drain: this stage's loads are done
      if (stage + 1 < NSTG) STAGE_LOAD(stage + 1);
      const unsigned short* W = wbuf[stage & 1];
      ++stage;
      const u32x4* QW = (const u32x4*)W;
      const u32x4* KW = (const u32x4*)(W + 4096);
      const u32x4* VW = (const u32x4*)(W + 8192);
      const u32x4* CW = (const u32x4*)(W + 12288);

      // q,k (C: rows=e_local, cols=t), packed straight into score fragments
      u32x4 qf[4][2], kf[4][2];
#pragma unroll
      for (int mi = 0; mi < 4; ++mi) {
        f32x4 cq[4], ck[4];
#pragma unroll
        for (int s = 0; s < 4; ++s) { cq[s] = z4; ck[s] = z4; }
#pragma unroll
        for (int ks = 0; ks < 2; ++ks) {
          u32x4 wq = QW[(mi * 2 + ks) * 64 + lane];
#pragma unroll
          for (int s = 0; s < 4; ++s) cq[s] = mfma_full(wq, xf[s][ks], cq[s]);
          u32x4 wk = KW[(mi * 2 + ks) * 64 + lane];
#pragma unroll
          for (int s = 0; s < 4; ++s) ck[s] = mfma_full(wk, xf[s][ks], ck[s]);
        }
#pragma unroll
        for (int s = 0; s < 4; ++s) {
          qf[s][mi >> 1][2 * (mi & 1)] = pk2(cq[s][0], cq[s][1]);
          qf[s][mi >> 1][2 * (mi & 1) + 1] = pk2(cq[s][2], cq[s][3]);
          kf[s][mi >> 1][2 * (mi & 1)] = pk2(ck[s][0], ck[s][1]);
          kf[s][mi >> 1][2 * (mi & 1) + 1] = pk2(ck[s][2], ck[s][3]);
        }
      }
      // scores (K=64 over e) + softmax -> p fragments
      u32 p[4][2];
#pragma unroll
      for (int s = 0; s < 4; ++s) {
        f32x4 sc = mfma_full(kf[s][0], qf[s][0], z4);
        sc = mfma_full(kf[s][1], qf[s][1], sc);
        softmax_pk(sc, p[s][0], p[s][1]);
      }
      // v (C: rows=t, cols=e)
      u32 vf_[4][4][2];
#pragma unroll
      for (int nt = 0; nt < 4; ++nt) {
        f32x4 cv[4];
#pragma unroll
        for (int s = 0; s < 4; ++s) cv[s] = z4;
#pragma unroll
        for (int ks = 0; ks < 2; ++ks) {
          u32x4 w = VW[(nt * 2 + ks) * 64 + lane];
#pragma unroll
          for (int s = 0; s < 4; ++s) cv[s] = mfma_full(xf[s][ks], w, cv[s]);
        }
#pragma unroll
        for (int s = 0; s < 4; ++s) {
          vf_[s][nt][0] = pk2(cv[s][0], cv[s][1]);
          vf_[s][nt][1] = pk2(cv[s][2], cv[s][3]);
        }
      }
      // PV (K=16): C rows=e_local, cols=t; inject e=49 bias slot = 1
      u32x4 of_[4][2];
#pragma unroll
      for (int nt = 0; nt < 4; ++nt) {
#pragma unroll
        for (int s = 0; s < 4; ++s) {
          f32x4 c = mfma_hz(vf_[s][nt][0], vf_[s][nt][1], p[s][0], p[s][1], z4);
          if (nt == 3) c[1] = (g == 0) ? 1.0f : c[1];
          of_[s][nt >> 1][2 * (nt & 1)] = pk2(c[0], c[1]);
          of_[s][nt >> 1][2 * (nt & 1) + 1] = pk2(c[2], c[3]);
        }
      }
      // comb: accumulate (Wo@Wcat)_aug^T @ o DIRECTLY into h (residual chain)
#pragma unroll
      for (int ft = 0; ft < 4; ++ft) {
#pragma unroll
        for (int ks = 0; ks < 2; ++ks) {
          u32x4 w = CW[(ft * 2 + ks) * 64 + lane];
#pragma unroll
          for (int s = 0; s < 4; ++s) h[s][ft] = mfma_full(w, of_[s][ks], h[s][ft]);
        }
      }
    }

    // LN2 on x2 (= h), then h += b2 so FF2 accumulates into the residual
    {
      f32x4 gv[4], bv[4];
#pragma unroll
      for (int mi = 0; mi < 4; ++mi) {
        int off = layer * 64 + 16 * mi + 4 * g;
        gv[mi] = *(const f32x4*)(lg2 + off);
        bv[mi] = *(const f32x4*)(lb2 + off);
      }
#pragma unroll
      for (int s = 0; s < 4; ++s) ln_pack(h[s], gv, bv, g, xf[s]);
#pragma unroll
      for (int mi = 0; mi < 4; ++mi) {
        f32x4 bb = *(const f32x4*)(b2p + layer * 64 + 16 * mi + 4 * g);
#pragma unroll
        for (int s = 0; s < 4; ++s) h[s][mi] += bb;
      }
    }

    for (int fb = 0; fb < 8; ++fb) {
      __syncthreads();
      if (stage + 1 < NSTG) STAGE_LOAD(stage + 1);
      const unsigned short* W = wbuf[stage & 1];
      ++stage;
#pragma unroll
      for (int cr = 0; cr < 2; ++cr) {
        const u32x4* W1c = (const u32x4*)(W + cr * 8192);
        const u32x4* W2c = (const u32x4*)(W + cr * 8192 + 4096);
        u32x4 af[4][2];
#pragma unroll
        for (int jt = 0; jt < 4; ++jt) {
          f32x4 ca[4];
#pragma unroll
          for (int s = 0; s < 4; ++s) ca[s] = z4;
#pragma unroll
          for (int ks = 0; ks < 2; ++ks) {
            u32x4 w = W1c[(jt * 2 + ks) * 64 + lane];
#pragma unroll
            for (int s = 0; s < 4; ++s) ca[s] = mfma_full(w, xf[s][ks], ca[s]);
          }
#pragma unroll
          for (int s = 0; s < 4; ++s) {
            float r0 = fmaxf(ca[s][0], 0.f), r1 = fmaxf(ca[s][1], 0.f);
            float r2 = fmaxf(ca[s][2], 0.f), r3 = fmaxf(ca[s][3], 0.f);
            af[s][jt >> 1][2 * (jt & 1)] = pk2(r0, r1);
            af[s][jt >> 1][2 * (jt & 1) + 1] = pk2(r2, r3);
          }
        }
#pragma unroll
        for (int ft = 0; ft < 4; ++ft) {
#pragma unroll
          for (int ks = 0; ks < 2; ++ks) {
            u32x4 w = W2c[(ft * 2 + ks) * 64 + lane];
#pragma unroll
            for (int s = 0; s < 4; ++s) h[s][ft] = mfma_full(w, af[s][ks], h[s][ft]);
          }
        }
      }
    }
  }

  // ---- classification head on token 0 (col li==0); overlay scratch on wbuf ----
  __syncthreads();
  float* hs = (float*)&wbuf[0][0];  // [4 waves][4 samples][64]
  if (li == 0) {
#pragma unroll
    for (int s = 0; s < 4; ++s)
#pragma unroll
      for (int mi = 0; mi < 4; ++mi)
#pragma unroll
        for (int r = 0; r < 4; ++r)
          hs[(wv * 4 + s) * 64 + 16 * mi + 4 * g + r] = h[s][mi][r];
  }
  __syncthreads();
  if (lane < 40) {
    int smp = lane / 10, c = lane % 10;
    float acc = bc[c];
    const float* hrow = hs + (wv * 4 + smp) * 64;
    for (int d = 0; d < DM; ++d) acc += hrow[d] * Wc[d * NOUT + c];
    out[(size_t)(s0 + smp) * NOUT + c] = acc;
  }
}

extern "C" void kernel_launch(void* const* d_in, const int* in_sizes, int n_in,
                              void* d_out, int out_size, void* d_ws, size_t ws_size,
                              hipStream_t stream) {
  const float* x = (const float*)d_in[0];
  const float* Wq = (const float*)d_in[2];
  const float* bq = (const float*)d_in[3];
  const float* Wk = (const float*)d_in[4];
  const float* bk = (const float*)d_in[5];
  const float* Wv = (const float*)d_in[6];
  const float* bv = (const float*)d_in[7];
  const float* Wo = (const float*)d_in[8];
  const float* bo = (const float*)d_in[9];
  const float* Wcat = (const float*)d_in[10];
  const float* bcat = (const float*)d_in[11];
  const float* ln1_g = (const float*)d_in[12];
  const float* ln1_b = (const float*)d_in[13];
  const float* ln2_g = (const float*)d_in[14];
  const float* ln2_b = (const float*)d_in[15];
  const float* W1 = (const float*)d_in[16];
  const float* b1 = (const float*)d_in[17];
  const float* W2 = (const float*)d_in[18];
  const float* b2 = (const float*)d_in[19];
  const float* Wc = (const float*)d_in[20];
  const float* bc = (const float*)d_in[21];

  unsigned short* blob = (unsigned short*)d_ws;  // NSTG * 16384 ushorts
  float* fp = (float*)(blob + (size_t)NSTG * 16384);
  float* g1p = fp;
  float* b1p = g1p + 384;
  float* g2p = b1p + 384;
  float* b2lp = g2p + 384;
  float* b2p = b2lp + 384;

  prep_qkv_frag<<<72, 256, 0, stream>>>(Wq, bq, Wk, bk, Wv, bv, blob);
  prep_comb_frag<<<72, 256, 0, stream>>>(Wo, bo, Wcat, bcat, blob);
  prep_ff_frag<<<48, 256, 0, stream>>>(W1, b1, W2, blob);
  prep_small<<<1, 384, 0, stream>>>(ln1_g, ln1_b, ln2_g, ln2_b, b2, g1p, b1p, g2p, b2lp, b2p);

  transformer_kernel<<<NB / 16, 256, 0, stream>>>(
      x, (float*)d_out, blob, g1p, b1p, g2p, b2lp, b2p, Wc, bc);
}